// Round 1
// baseline (12801.726 us; speedup 1.0000x reference)
//
#include <hip/hip_runtime.h>
#include <hip/hip_bf16.h>
#include <stdint.h>

typedef short bf16x8 __attribute__((ext_vector_type(8)));
typedef float f32x4 __attribute__((ext_vector_type(4)));
typedef float f32x2 __attribute__((ext_vector_type(2)));

#define B_ 16
#define S_ 2048
#define H_ 512
#define NG 2048      // 4*H
#define KA 827
#define KP 832
#define NPOS (B_*S_)

// ---- workspace layout (bytes) ----
#define OFF_FLAGS 0                    // 16 u32
#define OFF_HBUF  256                  // u32[2][16][256] = 32768 B
#define OFF_XAUG  33280                // NPOS*KP*2 = 54,525,952
#define OFF_WIHB  54559232             // NG*KP*2   =  3,407,872
#define OFF_G     57967104             // NPOS*NG*2 = 134,217,728  (ends 192,184,832)

__device__ __forceinline__ unsigned short f2bf(float f){
  union { float f; unsigned u; } v; v.f = f;
  unsigned u = v.u;
  unsigned r = (u + 0x7FFFu + ((u >> 16) & 1u)) >> 16;
  return (unsigned short)r;
}
__device__ __forceinline__ float bf2f(unsigned short s){
  union { unsigned u; float f; } v; v.u = ((unsigned)s) << 16;
  return v.f;
}
__device__ __forceinline__ float sigf(float x){ return 1.0f / (1.0f + __expf(-x)); }
__device__ __forceinline__ float tanhfast(float x){ return 1.0f - 2.0f / (__expf(2.0f*x) + 1.0f); }

// ---------------- init: zero flags + h exchange buffers ----------------
__global__ void initk(unsigned* ws){
  int idx = blockIdx.x*256 + threadIdx.x;
  if (idx < 8256) ws[idx] = 0;   // covers flags(64B)+pad+hbuf(32768B) = 33024 B
}

// ---------------- windowed signatures -> x_aug (bf16, K padded to 832) ----------------
// block bid handles position p = bid = s*16 + b  (s = bid>>4, b = bid&15)
__global__ __launch_bounds__(256) void sigk(const float* __restrict__ x,
                                            unsigned short* __restrict__ xaug){
  const int bid = blockIdx.x;
  const int s = bid >> 4, b = bid & 15;
  const int tid = threadIdx.x;
  __shared__ float win[10][9];
  __shared__ float s1b[2][9];
  __shared__ float s2b[2][81];
  if (tid < 90){
    int w = tid / 9, d = tid - w*9;
    int idx = s - 9 + w; if (idx < 0) idx = 0;
    win[w][d] = (d < 8) ? x[((size_t)b*S_ + idx)*8 + d] : (float)idx * (1.0f/2047.0f);
  }
  if (tid < 81) s2b[0][tid] = 0.0f;
  if (tid < 9)  s1b[0][tid] = 0.0f;
  __syncthreads();
  // thread owns s3 elements e = tid, tid+243, tid+486 (same j,k; i differs by 3)
  const int i0 = tid / 81;
  const int jj = (tid / 9) % 9;
  const int kk = tid % 9;
  float r0 = 0.0f, r1 = 0.0f, r2 = 0.0f;
  int p = 0;
  for (int w = 0; w < 10; ++w){
    if (tid < 243){
      float dj  = win[w][jj]   - (w ? win[w-1][jj]   : 0.0f);
      float dk  = win[w][kk]   - (w ? win[w-1][kk]   : 0.0f);
      float di0 = win[w][i0]   - (w ? win[w-1][i0]   : 0.0f);
      float di1 = win[w][i0+3] - (w ? win[w-1][i0+3] : 0.0f);
      float di2 = win[w][i0+6] - (w ? win[w-1][i0+6] : 0.0f);
      float e2 = 0.5f * dj * dk;
      float e3 = dj * dk * (1.0f/6.0f);
      r0 += s2b[p][i0*9+jj]*dk     + s1b[p][i0]*e2   + di0*e3;
      r1 += s2b[p][(i0+3)*9+jj]*dk + s1b[p][i0+3]*e2 + di1*e3;
      r2 += s2b[p][(i0+6)*9+jj]*dk + s1b[p][i0+6]*e2 + di2*e3;
    }
    if (tid < 81){
      int si = tid / 9, sj = tid - si*9;
      float dsi = win[w][si] - (w ? win[w-1][si] : 0.0f);
      float dsj = win[w][sj] - (w ? win[w-1][sj] : 0.0f);
      s2b[p^1][tid] = s2b[p][tid] + s1b[p][si]*dsj + 0.5f*dsi*dsj;
    }
    if (tid < 9){
      float dt = win[w][tid] - (w ? win[w-1][tid] : 0.0f);
      s1b[p^1][tid] = s1b[p][tid] + dt;
    }
    __syncthreads();
    p ^= 1;
  }
  unsigned short* row = xaug + (size_t)bid * KP;
  if (tid < 8)  row[tid]      = f2bf(x[((size_t)b*S_ + s)*8 + tid]);
  if (tid < 9)  row[8 + tid]  = f2bf(s1b[p][tid]);
  if (tid < 81) row[17 + tid] = f2bf(s2b[p][tid]);
  if (tid < 243){
    row[98 + tid]       = f2bf(r0);
    row[98 + tid + 243] = f2bf(r1);
    row[98 + tid + 486] = f2bf(r2);
  }
  if (tid < KP - KA) row[KA + tid] = 0;  // zero pad
}

// ---------------- W_ih f32 (2048x827) -> bf16 (2048x832 padded) ----------------
__global__ void convk(const float* __restrict__ W, unsigned short* __restrict__ o){
  int idx = blockIdx.x*256 + threadIdx.x;
  if (idx >= NG*KP) return;
  int n = idx / KP, k = idx - n*KP;
  o[idx] = (k < KA) ? f2bf(W[(size_t)n*KA + k]) : (unsigned short)0;
}

// ---------------- G = x_aug @ W_ih.T  (bf16 out) ----------------
// 128x128 tile, BK=32, 4 waves each 64x64
__global__ __launch_bounds__(256) void gemmk(const unsigned short* __restrict__ A,
                                             const unsigned short* __restrict__ Bw,
                                             unsigned short* __restrict__ G){
  __shared__ unsigned short as[128][40];   // stride 40 bf16 (80B) to spread banks
  __shared__ unsigned short bs[128][40];
  const int tid = threadIdx.x;
  const int l = tid & 63, w = tid >> 6;
  const int wr = w >> 1, wc = w & 1;
  const int M0 = blockIdx.x * 128, N0 = blockIdx.y * 128;
  f32x4 acc[4][4];
  for (int i=0;i<4;i++) for (int j2=0;j2<4;j2++) acc[i][j2] = (f32x4){0,0,0,0};
  const int lrow = l & 15, kq8 = (l >> 4) * 8;
  for (int kt = 0; kt < 26; ++kt){
    const int kbase = kt * 32;
    for (int c = tid; c < 512; c += 256){
      int row = c >> 2, kc = (c & 3) * 8;
      uint4 va = *(const uint4*)(A  + (size_t)(M0 + row)*KP + kbase + kc);
      *(uint4*)(&as[row][kc]) = va;
      uint4 vb = *(const uint4*)(Bw + (size_t)(N0 + row)*KP + kbase + kc);
      *(uint4*)(&bs[row][kc]) = vb;
    }
    __syncthreads();
    bf16x8 af[4], bfv[4];
    for (int i=0;i<4;i++)    af[i]  = *(const bf16x8*)(&as[wr*64 + i*16 + lrow][kq8]);
    for (int j2=0;j2<4;j2++) bfv[j2] = *(const bf16x8*)(&bs[wc*64 + j2*16 + lrow][kq8]);
    for (int i=0;i<4;i++)
      for (int j2=0;j2<4;j2++)
        acc[i][j2] = __builtin_amdgcn_mfma_f32_16x16x32_bf16(af[i], bfv[j2], acc[i][j2], 0, 0, 0);
    __syncthreads();
  }
  const int rq = (l >> 4) * 4;
  for (int i=0;i<4;i++){
    for (int q=0;q<4;q++){
      int grow_ = M0 + wr*64 + i*16 + rq + q;
      unsigned short* gout = G + (size_t)grow_*NG + N0 + wc*64 + lrow;
      for (int j2=0;j2<4;j2++)
        gout[j2*16] = f2bf(acc[i][j2][q]);
    }
  }
}

// ---------------- LSTM recurrence: 16 blocks, W_hh slice in registers ----------------
// block j owns h lanes k in [j*32, j*32+32); gate rows {g*512 + j*32 + c}
__global__ __launch_bounds__(256, 1) void recurk(const float* __restrict__ Whh,
    const float* __restrict__ bih, const float* __restrict__ bhh,
    const unsigned short* __restrict__ G, float* __restrict__ out,
    unsigned* __restrict__ flags, unsigned* __restrict__ hbuf){
  const int j = blockIdx.x;
  const int tid = threadIdx.x;
  const int w = tid >> 6, l = tid & 63;
  const int b = l & 15, kq = l >> 4;
  __shared__ float gates[128*17];   // [gate row r][batch], stride 17 to spread banks

  // A fragments (W_hh slice, bf16) resident in registers: a[mt][k-step]
  bf16x8 a[2][16];
  for (int mt = 0; mt < 2; ++mt){
    int grow_ = w*512 + j*32 + mt*16 + (l & 15);
    const float* wrow = Whh + (size_t)grow_ * H_;
    for (int kk2 = 0; kk2 < 16; ++kk2){
      int k0 = kk2*32 + kq*8;
      float4 v0 = *(const float4*)(wrow + k0);
      float4 v1 = *(const float4*)(wrow + k0 + 4);
      bf16x8 av;
      av[0] = (short)f2bf(v0.x); av[1] = (short)f2bf(v0.y);
      av[2] = (short)f2bf(v0.z); av[3] = (short)f2bf(v0.w);
      av[4] = (short)f2bf(v1.x); av[5] = (short)f2bf(v1.y);
      av[6] = (short)f2bf(v1.z); av[7] = (short)f2bf(v1.w);
      a[mt][kk2] = av;
    }
  }
  const int growc0 = w*512 + j*32 + kq*4;   // C-row mapping for tile 0
  const int growc1 = growc0 + 16;           // tile 1
  float bias0[4], bias1[4];
  for (int q=0;q<4;q++){
    bias0[q] = bih[growc0+q] + bhh[growc0+q];
    bias1[q] = bih[growc1+q] + bhh[growc1+q];
  }
  const int ub = tid & 15, ucp = tid >> 4;  // update-phase mapping: batch, k-pair
  float cr0 = 0.0f, cr1 = 0.0f;

  for (int t = 0; t < S_; ++t){
    // G loads first (independent of h) so latency hides under the flag spin
    const unsigned short* gp = G + ((size_t)t*16 + b) * NG;
    const short4 g0 = *(const short4*)(gp + growc0);
    const short4 g1 = *(const short4*)(gp + growc1);
    if (t){
      for (;;){
        unsigned f = __hip_atomic_load(flags + (l & 15), __ATOMIC_RELAXED, __HIP_MEMORY_SCOPE_AGENT);
        if (__all((int)f >= t)) break;
        __builtin_amdgcn_s_sleep(2);
      }
      __threadfence();   // acquire: invalidate L1/L2 so h loads below see fresh data
    }
    f32x4 acc0 = (f32x4){0,0,0,0}, acc1 = (f32x4){0,0,0,0};
    const uint4* hsrc = (const uint4*)(hbuf + (size_t)(t & 1)*4096 + b*256 + kq*4);
    for (int kk2 = 0; kk2 < 16; ++kk2){
      uint4 hv = hsrc[kk2*4];
      bf16x8 bv = __builtin_bit_cast(bf16x8, hv);
      acc0 = __builtin_amdgcn_mfma_f32_16x16x32_bf16(a[0][kk2], bv, acc0, 0, 0, 0);
      acc1 = __builtin_amdgcn_mfma_f32_16x16x32_bf16(a[1][kk2], bv, acc1, 0, 0, 0);
    }
    float gadd0[4] = { bf2f((unsigned short)g0.x), bf2f((unsigned short)g0.y),
                       bf2f((unsigned short)g0.z), bf2f((unsigned short)g0.w) };
    float gadd1[4] = { bf2f((unsigned short)g1.x), bf2f((unsigned short)g1.y),
                       bf2f((unsigned short)g1.z), bf2f((unsigned short)g1.w) };
    for (int q=0;q<4;q++){
      gates[(32*w + kq*4 + q)*17 + b]      = acc0[q] + gadd0[q] + bias0[q];
      gates[(32*w + 16 + kq*4 + q)*17 + b] = acc1[q] + gadd1[q] + bias1[q];
    }
    __syncthreads();
    {
      const int e0 = 2*ucp;
      float i0v = sigf(gates[(e0)*17 + ub]);
      float f0v = sigf(gates[(32+e0)*17 + ub]);
      float g0v = tanhfast(gates[(64+e0)*17 + ub]);
      float o0v = sigf(gates[(96+e0)*17 + ub]);
      float i1v = sigf(gates[(e0+1)*17 + ub]);
      float f1v = sigf(gates[(32+e0+1)*17 + ub]);
      float g1v = tanhfast(gates[(64+e0+1)*17 + ub]);
      float o1v = sigf(gates[(96+e0+1)*17 + ub]);
      cr0 = f0v*cr0 + i0v*g0v;
      cr1 = f1v*cr1 + i1v*g1v;
      float h0 = o0v * tanhfast(cr0);
      float h1 = o1v * tanhfast(cr1);
      f32x2 hv2; hv2[0] = h0; hv2[1] = h1;
      __builtin_nontemporal_store(hv2, (f32x2*)(out + ((size_t)ub*S_ + t)*H_ + j*32 + e0));
      unsigned packed = (unsigned)f2bf(h0) | ((unsigned)f2bf(h1) << 16);
      hbuf[(size_t)((t+1) & 1)*4096 + ub*256 + j*16 + ucp] = packed;
      if (t == S_ - 1){
        float* hn = out + (size_t)B_*S_*H_;
        float* cn = hn + B_*H_;
        hn[ub*H_ + j*32 + e0]     = h0;
        hn[ub*H_ + j*32 + e0 + 1] = h1;
        cn[ub*H_ + j*32 + e0]     = cr0;
        cn[ub*H_ + j*32 + e0 + 1] = cr1;
      }
    }
    __syncthreads();
    if (tid == 0 && t < S_ - 1){
      __threadfence();   // release: push h slice to L3 before raising flag
      __hip_atomic_store(flags + j, (unsigned)(t + 1), __ATOMIC_RELAXED, __HIP_MEMORY_SCOPE_AGENT);
    }
  }
}

extern "C" void kernel_launch(void* const* d_in, const int* in_sizes, int n_in,
                              void* d_out, int out_size, void* d_ws, size_t ws_size,
                              hipStream_t stream){
  const float* x   = (const float*)d_in[0];
  const float* Wih = (const float*)d_in[1];
  const float* Whh = (const float*)d_in[2];
  const float* bih = (const float*)d_in[3];
  const float* bhh = (const float*)d_in[4];
  float* out = (float*)d_out;
  char* ws = (char*)d_ws;
  unsigned* flags       = (unsigned*)(ws + OFF_FLAGS);
  unsigned* hbuf        = (unsigned*)(ws + OFF_HBUF);
  unsigned short* xaug  = (unsigned short*)(ws + OFF_XAUG);
  unsigned short* wihb  = (unsigned short*)(ws + OFF_WIHB);
  unsigned short* G     = (unsigned short*)(ws + OFF_G);

  initk<<<33, 256, 0, stream>>>((unsigned*)ws);
  sigk<<<NPOS, 256, 0, stream>>>(x, xaug);
  convk<<<(NG*KP + 255)/256, 256, 0, stream>>>(Wih, wihb);
  gemmk<<<dim3(256, 16), 256, 0, stream>>>(xaug, wihb, G);
  recurk<<<16, 256, 0, stream>>>(Whh, bih, bhh, G, out, flags, hbuf);
}

// Round 3
// 7834.898 us; speedup vs baseline: 1.6339x; 1.6339x over previous
//
#include <hip/hip_runtime.h>
#include <hip/hip_bf16.h>
#include <stdint.h>

typedef short bf16x8 __attribute__((ext_vector_type(8)));
typedef float f32x4 __attribute__((ext_vector_type(4)));

#define B_ 16
#define S_ 2048
#define H_ 512
#define NG 2048      // 4*H
#define KA 827
#define KP 832
#define NPOS (B_*S_)

// ---- workspace layout (bytes) ----
// ring gets a DEDICATED region (no overlap with cacheable-written buffers, so no
// dirty-line eviction can clobber it). 4 slots x u64[16 batch][128] = 64 KiB.
#define OFF_RING 0
#define RING_U64_PER_SLOT 2048
#define RING_SLOTS 4
#define OFF_XAUG 65536                 // NPOS*KP*2 = 54,525,952
#define OFF_WIHB 54591488              // NG*KP*2   =  3,407,872
#define OFF_G    57999360              // NPOS*NG*2 = 134,217,728 (ends 192,217,088)
#define SENT64 0x7F807F807F807F80ull   // 4x bf16 +inf; |h|<1 can never produce this

__device__ __forceinline__ unsigned short f2bf(float f){
  union { float f; unsigned u; } v; v.f = f;
  unsigned u = v.u;
  unsigned r = (u + 0x7FFFu + ((u >> 16) & 1u)) >> 16;
  return (unsigned short)r;
}
__device__ __forceinline__ float bf2f(unsigned short s){
  union { unsigned u; float f; } v; v.u = ((unsigned)s) << 16;
  return v.f;
}
__device__ __forceinline__ float sigf(float x){ return 1.0f / (1.0f + __expf(-x)); }
__device__ __forceinline__ float tanhfast(float x){ return 1.0f - 2.0f / (__expf(2.0f*x) + 1.0f); }

// ---------------- ring sentinel init (atomic RMW so it reaches the coherence point) ----------------
__global__ void ringinit(unsigned long long* __restrict__ ring){
  int i = blockIdx.x*256 + threadIdx.x;
  if (i < RING_SLOTS*RING_U64_PER_SLOT)
    __hip_atomic_exchange(ring + i, SENT64, __ATOMIC_RELAXED, __HIP_MEMORY_SCOPE_AGENT);
}

// ---------------- windowed signatures -> x_aug (bf16, K padded to 832) ----------------
__global__ __launch_bounds__(256) void sigk(const float* __restrict__ x,
                                            unsigned short* __restrict__ xaug){
  const int bid = blockIdx.x;
  const int s = bid >> 4, b = bid & 15;
  const int tid = threadIdx.x;
  __shared__ float win[10][9];
  __shared__ float s1b[2][9];
  __shared__ float s2b[2][81];
  if (tid < 90){
    int w = tid / 9, d = tid - w*9;
    int idx = s - 9 + w; if (idx < 0) idx = 0;
    win[w][d] = (d < 8) ? x[((size_t)b*S_ + idx)*8 + d] : (float)idx * (1.0f/2047.0f);
  }
  if (tid < 81) s2b[0][tid] = 0.0f;
  if (tid < 9)  s1b[0][tid] = 0.0f;
  __syncthreads();
  const int i0 = tid / 81;
  const int jj = (tid / 9) % 9;
  const int kk = tid % 9;
  float r0 = 0.0f, r1 = 0.0f, r2 = 0.0f;
  int p = 0;
  for (int w = 0; w < 10; ++w){
    if (tid < 243){
      float dj  = win[w][jj]   - (w ? win[w-1][jj]   : 0.0f);
      float dk  = win[w][kk]   - (w ? win[w-1][kk]   : 0.0f);
      float di0 = win[w][i0]   - (w ? win[w-1][i0]   : 0.0f);
      float di1 = win[w][i0+3] - (w ? win[w-1][i0+3] : 0.0f);
      float di2 = win[w][i0+6] - (w ? win[w-1][i0+6] : 0.0f);
      float e2 = 0.5f * dj * dk;
      float e3 = dj * dk * (1.0f/6.0f);
      r0 += s2b[p][i0*9+jj]*dk     + s1b[p][i0]*e2   + di0*e3;
      r1 += s2b[p][(i0+3)*9+jj]*dk + s1b[p][i0+3]*e2 + di1*e3;
      r2 += s2b[p][(i0+6)*9+jj]*dk + s1b[p][i0+6]*e2 + di2*e3;
    }
    if (tid < 81){
      int si = tid / 9, sj = tid - si*9;
      float dsi = win[w][si] - (w ? win[w-1][si] : 0.0f);
      float dsj = win[w][sj] - (w ? win[w-1][sj] : 0.0f);
      s2b[p^1][tid] = s2b[p][tid] + s1b[p][si]*dsj + 0.5f*dsi*dsj;
    }
    if (tid < 9){
      float dt = win[w][tid] - (w ? win[w-1][tid] : 0.0f);
      s1b[p^1][tid] = s1b[p][tid] + dt;
    }
    __syncthreads();
    p ^= 1;
  }
  unsigned short* row = xaug + (size_t)bid * KP;
  if (tid < 8)  row[tid]      = f2bf(x[((size_t)b*S_ + s)*8 + tid]);
  if (tid < 9)  row[8 + tid]  = f2bf(s1b[p][tid]);
  if (tid < 81) row[17 + tid] = f2bf(s2b[p][tid]);
  if (tid < 243){
    row[98 + tid]       = f2bf(r0);
    row[98 + tid + 243] = f2bf(r1);
    row[98 + tid + 486] = f2bf(r2);
  }
  if (tid < KP - KA) row[KA + tid] = 0;
}

// ---------------- W_ih f32 (2048x827) -> bf16 (2048x832 padded) ----------------
__global__ void convk(const float* __restrict__ W, unsigned short* __restrict__ o){
  int idx = blockIdx.x*256 + threadIdx.x;
  if (idx >= NG*KP) return;
  int n = idx / KP, k = idx - n*KP;
  o[idx] = (k < KA) ? f2bf(W[(size_t)n*KA + k]) : (unsigned short)0;
}

// ---------------- G = x_aug @ W_ih.T  (bf16 out) ----------------
__global__ __launch_bounds__(256) void gemmk(const unsigned short* __restrict__ A,
                                             const unsigned short* __restrict__ Bw,
                                             unsigned short* __restrict__ G){
  __shared__ unsigned short as[128][40];
  __shared__ unsigned short bs[128][40];
  const int tid = threadIdx.x;
  const int l = tid & 63, w = tid >> 6;
  const int wr = w >> 1, wc = w & 1;
  const int M0 = blockIdx.x * 128, N0 = blockIdx.y * 128;
  f32x4 acc[4][4];
  for (int i=0;i<4;i++) for (int j2=0;j2<4;j2++) acc[i][j2] = (f32x4){0,0,0,0};
  const int lrow = l & 15, kq8 = (l >> 4) * 8;
  for (int kt = 0; kt < 26; ++kt){
    const int kbase = kt * 32;
    for (int c = tid; c < 512; c += 256){
      int row = c >> 2, kc = (c & 3) * 8;
      uint4 va = *(const uint4*)(A  + (size_t)(M0 + row)*KP + kbase + kc);
      *(uint4*)(&as[row][kc]) = va;
      uint4 vb = *(const uint4*)(Bw + (size_t)(N0 + row)*KP + kbase + kc);
      *(uint4*)(&bs[row][kc]) = vb;
    }
    __syncthreads();
    bf16x8 af[4], bfv[4];
    for (int i=0;i<4;i++)    af[i]  = *(const bf16x8*)(&as[wr*64 + i*16 + lrow][kq8]);
    for (int j2=0;j2<4;j2++) bfv[j2] = *(const bf16x8*)(&bs[wc*64 + j2*16 + lrow][kq8]);
    for (int i=0;i<4;i++)
      for (int j2=0;j2<4;j2++)
        acc[i][j2] = __builtin_amdgcn_mfma_f32_16x16x32_bf16(af[i], bfv[j2], acc[i][j2], 0, 0, 0);
    __syncthreads();
  }
  const int rq = (l >> 4) * 4;
  for (int i=0;i<4;i++){
    for (int q=0;q<4;q++){
      int grow_ = M0 + wr*64 + i*16 + rq + q;
      unsigned short* gout = G + (size_t)grow_*NG + N0 + wc*64 + lrow;
      for (int j2=0;j2<4;j2++)
        gout[j2*16] = f2bf(acc[i][j2][q]);
    }
  }
}

// ---------------- LSTM recurrence: 64 autonomous waves, sentinel ring ----------------
// wave W owns h indices [W*8, W*8+8) with ALL 4 gates (i/f in MFMA0, g/o in MFMA1).
// C layout (16x16x32): col=lane&15 (batch), row=(lane>>4)*4+q. Lanes kq<2 hold i/g
// rows, kq>=2 hold f/o rows for the same h index; one __shfl_xor(32) pairs them.
// h exchange: 4-slot ring; writes = atomic exchange (reaches coherence point),
// reads = relaxed agent atomic loads (R0-proven to see remote updates).
// Slot for step t reused at t+4; re-armed to sentinel at step t+2 (safe: a wave
// past poll of slot t+1 implies every wave consumed slot t; vmcnt(0) after each
// poll guarantees re-arms drain before the slot's next fresh write).
__global__ __launch_bounds__(64, 1) void recurk(const float* __restrict__ Whh,
    const float* __restrict__ bih, const float* __restrict__ bhh,
    const unsigned short* __restrict__ G, float* __restrict__ out,
    unsigned long long* __restrict__ ring){
  const int W = ((blockIdx.x & 7) << 3) | (blockIdx.x >> 3);  // G-line-sharing waves on one XCD
  const int l = threadIdx.x;
  const int b = l & 15, kq = l >> 4;
  const int hbase = W * 8;

  // A fragments resident in registers (128 VGPRs)
  bf16x8 a0[16], a1[16];
  {
    const int p = l & 15;
    const int arow0 = (p < 8) ? (hbase + p) : (512 + hbase + (p - 8));
    const int arow1 = arow0 + 1024;
    const float* w0 = Whh + (size_t)arow0 * H_;
    const float* w1 = Whh + (size_t)arow1 * H_;
    for (int kk2 = 0; kk2 < 16; ++kk2){
      const int k0 = kk2*32 + kq*8;
      float4 v0 = *(const float4*)(w0 + k0);
      float4 v1 = *(const float4*)(w0 + k0 + 4);
      bf16x8 av;
      av[0]=(short)f2bf(v0.x); av[1]=(short)f2bf(v0.y); av[2]=(short)f2bf(v0.z); av[3]=(short)f2bf(v0.w);
      av[4]=(short)f2bf(v1.x); av[5]=(short)f2bf(v1.y); av[6]=(short)f2bf(v1.z); av[7]=(short)f2bf(v1.w);
      a0[kk2] = av;
      float4 u0 = *(const float4*)(w1 + k0);
      float4 u1 = *(const float4*)(w1 + k0 + 4);
      bf16x8 bv2;
      bv2[0]=(short)f2bf(u0.x); bv2[1]=(short)f2bf(u0.y); bv2[2]=(short)f2bf(u0.z); bv2[3]=(short)f2bf(u0.w);
      bv2[4]=(short)f2bf(u1.x); bv2[5]=(short)f2bf(u1.y); bv2[6]=(short)f2bf(u1.z); bv2[7]=(short)f2bf(u1.w);
      a1[kk2] = bv2;
    }
  }
  const int col0 = ((kq < 2) ? (kq*4) : (512 + (kq-2)*4)) + hbase;
  const int col1 = col0 + 1024;
  float bias0[4], bias1[4];
  #pragma unroll
  for (int q=0;q<4;q++){
    bias0[q] = bih[col0+q] + bhh[col0+q];
    bias1[q] = bih[col1+q] + bhh[col1+q];
  }
  const bool low = (kq < 2);
  const int hcol = hbase + (low ? kq*4 : (kq-2)*4);
  const size_t ownw = (size_t)b*128 + W*2 + kq;   // this low-lane's ring word (u64 index in slot)
  float cr[4] = {0,0,0,0};

  for (int t = 0; t < S_; ++t){
    // G prefetch (cacheable) issued before the poll; latency hides under the spin
    const unsigned short* gp = G + ((size_t)t*16 + b) * NG;
    const short4 g0 = *(const short4*)(gp + col0);
    const short4 g1 = *(const short4*)(gp + col1);

    f32x4 acc0 = (f32x4){0,0,0,0}, acc1 = (f32x4){0,0,0,0};
    if (t){
      const unsigned long long* rp = ring + (size_t)((t-1) & 3)*RING_U64_PER_SLOT + b*128 + kq*2;
      unsigned long long rv[32];
      for (;;){
        #pragma unroll
        for (int i = 0; i < 16; ++i){
          rv[2*i]   = __hip_atomic_load(rp + i*8,     __ATOMIC_RELAXED, __HIP_MEMORY_SCOPE_AGENT);
          rv[2*i+1] = __hip_atomic_load(rp + i*8 + 1, __ATOMIC_RELAXED, __HIP_MEMORY_SCOPE_AGENT);
        }
        unsigned ok = 1;
        #pragma unroll
        for (int i = 0; i < 32; ++i) ok &= (rv[i] != SENT64);
        if (__all(ok)) break;
      }
      // drain everything: guarantees our step-(t-1) ops and prior re-arms are at L3
      asm volatile("s_waitcnt vmcnt(0)" ::: "memory");
      // re-arm own words of slot (t-2) for reuse at step t+2
      if (t >= 2 && low)
        __hip_atomic_exchange(ring + (size_t)((t-2) & 3)*RING_U64_PER_SLOT + ownw,
                              SENT64, __ATOMIC_RELAXED, __HIP_MEMORY_SCOPE_AGENT);
      #pragma unroll
      for (int kk2 = 0; kk2 < 16; ++kk2){
        uint2 lo = __builtin_bit_cast(uint2, rv[2*kk2]);
        uint2 hi = __builtin_bit_cast(uint2, rv[2*kk2+1]);
        uint4 u; u.x = lo.x; u.y = lo.y; u.z = hi.x; u.w = hi.y;
        bf16x8 bv = __builtin_bit_cast(bf16x8, u);
        acc0 = __builtin_amdgcn_mfma_f32_16x16x32_bf16(a0[kk2], bv, acc0, 0, 0, 0);
        acc1 = __builtin_amdgcn_mfma_f32_16x16x32_bf16(a1[kk2], bv, acc1, 0, 0, 0);
      }
    }
    float ga0[4] = { bf2f((unsigned short)g0.x), bf2f((unsigned short)g0.y),
                     bf2f((unsigned short)g0.z), bf2f((unsigned short)g0.w) };
    float ga1[4] = { bf2f((unsigned short)g1.x), bf2f((unsigned short)g1.y),
                     bf2f((unsigned short)g1.z), bf2f((unsigned short)g1.w) };
    float own0[4], own1[4], oth0[4], oth1[4];
    #pragma unroll
    for (int q=0;q<4;q++){
      own0[q] = acc0[q] + ga0[q] + bias0[q];
      own1[q] = acc1[q] + ga1[q] + bias1[q];
    }
    #pragma unroll
    for (int q=0;q<4;q++){
      oth0[q] = __shfl_xor(own0[q], 32, 64);
      oth1[q] = __shfl_xor(own1[q], 32, 64);
    }
    float h4[4];
    #pragma unroll
    for (int q=0;q<4;q++){
      float iv = low ? own0[q] : oth0[q];
      float fv = low ? oth0[q] : own0[q];
      float gv = low ? own1[q] : oth1[q];
      float ov = low ? oth1[q] : own1[q];
      cr[q] = sigf(fv)*cr[q] + sigf(iv)*tanhfast(gv);
      h4[q] = sigf(ov)*tanhfast(cr[q]);
    }
    if (low){
      // publish h FIRST (atomic exchange = guaranteed at coherence point)
      if (t < S_ - 1){
        unsigned long long pk = (unsigned long long)f2bf(h4[0])
                              | ((unsigned long long)f2bf(h4[1]) << 16)
                              | ((unsigned long long)f2bf(h4[2]) << 32)
                              | ((unsigned long long)f2bf(h4[3]) << 48);
        __hip_atomic_exchange(ring + (size_t)(t & 3)*RING_U64_PER_SLOT + ownw,
                              pk, __ATOMIC_RELAXED, __HIP_MEMORY_SCOPE_AGENT);
      }
      f32x4 hw4; hw4[0]=h4[0]; hw4[1]=h4[1]; hw4[2]=h4[2]; hw4[3]=h4[3];
      __builtin_nontemporal_store(hw4, (f32x4*)(out + ((size_t)b*S_ + t)*H_ + hcol));
      if (t == S_ - 1){
        float* hn = out + (size_t)B_*S_*H_;
        float* cn = hn + B_*H_;
        #pragma unroll
        for (int q=0;q<4;q++){
          hn[b*H_ + hcol + q] = h4[q];
          cn[b*H_ + hcol + q] = cr[q];
        }
      }
    }
  }
}

extern "C" void kernel_launch(void* const* d_in, const int* in_sizes, int n_in,
                              void* d_out, int out_size, void* d_ws, size_t ws_size,
                              hipStream_t stream){
  const float* x   = (const float*)d_in[0];
  const float* Wih = (const float*)d_in[1];
  const float* Whh = (const float*)d_in[2];
  const float* bih = (const float*)d_in[3];
  const float* bhh = (const float*)d_in[4];
  float* out = (float*)d_out;
  char* ws = (char*)d_ws;
  unsigned long long* ring = (unsigned long long*)(ws + OFF_RING);
  unsigned short* xaug     = (unsigned short*)(ws + OFF_XAUG);
  unsigned short* wihb     = (unsigned short*)(ws + OFF_WIHB);
  unsigned short* G        = (unsigned short*)(ws + OFF_G);

  ringinit<<<32, 256, 0, stream>>>(ring);
  sigk<<<NPOS, 256, 0, stream>>>(x, xaug);
  convk<<<(NG*KP + 255)/256, 256, 0, stream>>>(Wih, wihb);
  gemmk<<<dim3(256, 16), 256, 0, stream>>>(xaug, wihb, G);
  recurk<<<64, 64, 0, stream>>>(Whh, bih, bhh, G, out, ring);
}

// Round 7
// 6750.754 us; speedup vs baseline: 1.8963x; 1.1606x over previous
//
#include <hip/hip_runtime.h>
#include <hip/hip_bf16.h>
#include <stdint.h>

typedef short bf16x8 __attribute__((ext_vector_type(8)));
typedef float f32x4 __attribute__((ext_vector_type(4)));

#define B_ 16
#define S_ 2048
#define H_ 512
#define NG 2048      // 4*H
#define KA 827
#define KP 832
#define NPOS (B_*S_)

// ---- workspace layout (bytes) ----
// ring + flags overlay xaug (dead after gemmk; sentk re-initializes, its plain
// stores reach L3 via the dispatch-end writeback proven by every passing round).
// ring: 2048 slots x 16 KiB, NO-REUSE (slot t written once at step t, read at t+1).
// flags: [step][wave] u32, NO-REUSE, zero-init; set (=1) by agent atomic exchange.
#define OFF_XAUG 0                     // NPOS*KP*2 = 54,525,952
#define OFF_WIHB 54525952              // NG*KP*2   =  3,407,872
#define OFF_G    57933824              // NPOS*NG*2 = 134,217,728 (ends 192,151,552)
#define OFF_RING 0                     // 33,554,432 B
#define RING_U64_PER_SLOT 2048
#define OFF_FLAG 33554432              // 2048*64*4 = 524,288 B (ends 34,078,720 < xaug end)
#define SENT32 0x7F807F80u
#define SENT64 0x7F807F807F807F80ull   // 4x bf16 +inf; |h|<1 can never produce this

__device__ __forceinline__ unsigned short f2bf(float f){
  union { float f; unsigned u; } v; v.f = f;
  unsigned u = v.u;
  unsigned r = (u + 0x7FFFu + ((u >> 16) & 1u)) >> 16;
  return (unsigned short)r;
}
__device__ __forceinline__ float bf2f(unsigned short s){
  union { unsigned u; float f; } v; v.u = ((unsigned)s) << 16;
  return v.f;
}
__device__ __forceinline__ float sigf(float x){ return 1.0f / (1.0f + __expf(-x)); }
__device__ __forceinline__ float tanhfast(float x){ return 1.0f - 2.0f / (__expf(2.0f*x) + 1.0f); }

// ---------------- windowed signatures -> x_aug (bf16, K padded to 832) ----------------
__global__ __launch_bounds__(256) void sigk(const float* __restrict__ x,
                                            unsigned short* __restrict__ xaug){
  const int bid = blockIdx.x;
  const int s = bid >> 4, b = bid & 15;
  const int tid = threadIdx.x;
  __shared__ float win[10][9];
  __shared__ float s1b[2][9];
  __shared__ float s2b[2][81];
  if (tid < 90){
    int w = tid / 9, d = tid - w*9;
    int idx = s - 9 + w; if (idx < 0) idx = 0;
    win[w][d] = (d < 8) ? x[((size_t)b*S_ + idx)*8 + d] : (float)idx * (1.0f/2047.0f);
  }
  if (tid < 81) s2b[0][tid] = 0.0f;
  if (tid < 9)  s1b[0][tid] = 0.0f;
  __syncthreads();
  const int i0 = tid / 81;
  const int jj = (tid / 9) % 9;
  const int kk = tid % 9;
  float r0 = 0.0f, r1 = 0.0f, r2 = 0.0f;
  int p = 0;
  for (int w = 0; w < 10; ++w){
    if (tid < 243){
      float dj  = win[w][jj]   - (w ? win[w-1][jj]   : 0.0f);
      float dk  = win[w][kk]   - (w ? win[w-1][kk]   : 0.0f);
      float di0 = win[w][i0]   - (w ? win[w-1][i0]   : 0.0f);
      float di1 = win[w][i0+3] - (w ? win[w-1][i0+3] : 0.0f);
      float di2 = win[w][i0+6] - (w ? win[w-1][i0+6] : 0.0f);
      float e2 = 0.5f * dj * dk;
      float e3 = dj * dk * (1.0f/6.0f);
      r0 += s2b[p][i0*9+jj]*dk     + s1b[p][i0]*e2   + di0*e3;
      r1 += s2b[p][(i0+3)*9+jj]*dk + s1b[p][i0+3]*e2 + di1*e3;
      r2 += s2b[p][(i0+6)*9+jj]*dk + s1b[p][i0+6]*e2 + di2*e3;
    }
    if (tid < 81){
      int si = tid / 9, sj = tid - si*9;
      float dsi = win[w][si] - (w ? win[w-1][si] : 0.0f);
      float dsj = win[w][sj] - (w ? win[w-1][sj] : 0.0f);
      s2b[p^1][tid] = s2b[p][tid] + s1b[p][si]*dsj + 0.5f*dsi*dsj;
    }
    if (tid < 9){
      float dt = win[w][tid] - (w ? win[w-1][tid] : 0.0f);
      s1b[p^1][tid] = s1b[p][tid] + dt;
    }
    __syncthreads();
    p ^= 1;
  }
  unsigned short* row = xaug + (size_t)bid * KP;
  if (tid < 8)  row[tid]      = f2bf(x[((size_t)b*S_ + s)*8 + tid]);
  if (tid < 9)  row[8 + tid]  = f2bf(s1b[p][tid]);
  if (tid < 81) row[17 + tid] = f2bf(s2b[p][tid]);
  if (tid < 243){
    row[98 + tid]       = f2bf(r0);
    row[98 + tid + 243] = f2bf(r1);
    row[98 + tid + 486] = f2bf(r2);
  }
  if (tid < KP - KA) row[KA + tid] = 0;
}

// ---------------- W_ih f32 (2048x827) -> bf16 (2048x832 padded) ----------------
__global__ void convk(const float* __restrict__ W, unsigned short* __restrict__ o){
  int idx = blockIdx.x*256 + threadIdx.x;
  if (idx >= NG*KP) return;
  int n = idx / KP, k = idx - n*KP;
  o[idx] = (k < KA) ? f2bf(W[(size_t)n*KA + k]) : (unsigned short)0;
}

// ---------------- G = x_aug @ W_ih.T  (bf16 out) ----------------
__global__ __launch_bounds__(256) void gemmk(const unsigned short* __restrict__ A,
                                             const unsigned short* __restrict__ Bw,
                                             unsigned short* __restrict__ G){
  __shared__ unsigned short as[128][40];
  __shared__ unsigned short bs[128][40];
  const int tid = threadIdx.x;
  const int l = tid & 63, w = tid >> 6;
  const int wr = w >> 1, wc = w & 1;
  const int M0 = blockIdx.x * 128, N0 = blockIdx.y * 128;
  f32x4 acc[4][4];
  for (int i=0;i<4;i++) for (int j2=0;j2<4;j2++) acc[i][j2] = (f32x4){0,0,0,0};
  const int lrow = l & 15, kq8 = (l >> 4) * 8;
  for (int kt = 0; kt < 26; ++kt){
    const int kbase = kt * 32;
    for (int c = tid; c < 512; c += 256){
      int row = c >> 2, kc = (c & 3) * 8;
      uint4 va = *(const uint4*)(A  + (size_t)(M0 + row)*KP + kbase + kc);
      *(uint4*)(&as[row][kc]) = va;
      uint4 vb = *(const uint4*)(Bw + (size_t)(N0 + row)*KP + kbase + kc);
      *(uint4*)(&bs[row][kc]) = vb;
    }
    __syncthreads();
    bf16x8 af[4], bfv[4];
    for (int i=0;i<4;i++)    af[i]  = *(const bf16x8*)(&as[wr*64 + i*16 + lrow][kq8]);
    for (int j2=0;j2<4;j2++) bfv[j2] = *(const bf16x8*)(&bs[wc*64 + j2*16 + lrow][kq8]);
    for (int i=0;i<4;i++)
      for (int j2=0;j2<4;j2++)
        acc[i][j2] = __builtin_amdgcn_mfma_f32_16x16x32_bf16(af[i], bfv[j2], acc[i][j2], 0, 0, 0);
    __syncthreads();
  }
  const int rq = (l >> 4) * 4;
  for (int i=0;i<4;i++){
    for (int q=0;q<4;q++){
      int grow_ = M0 + wr*64 + i*16 + rq + q;
      unsigned short* gout = G + (size_t)grow_*NG + N0 + wc*64 + lrow;
      for (int j2=0;j2<4;j2++)
        gout[j2*16] = f2bf(acc[i][j2][q]);
    }
  }
}

// ---------------- init: sentinel-fill ring (32 MiB) + zero flags (512 KiB) ----------------
// plain stores; dispatch-end writeback makes them visible at L3 (proven by every round).
__global__ __launch_bounds__(256) void sentk(uint4* __restrict__ base){
  const size_t i = (size_t)blockIdx.x*256 + threadIdx.x;   // 1040 blocks -> 266240 threads
  uint4 s; s.x = SENT32; s.y = SENT32; s.z = SENT32; s.w = SENT32;
  uint4 z; z.x = 0; z.y = 0; z.z = 0; z.w = 0;
  #pragma unroll
  for (int k = 0; k < 8; ++k){
    size_t j = i + (size_t)k*266240;                       // covers [0, 2,129,920) uint4
    base[j] = (j < 2097152) ? s : z;                       // ring sentinel | flag zero
  }
}

// ---------------- LSTM recurrence: 64 autonomous waves, flag-gated no-reuse ring ----------------
// wave W owns h indices [W*8, W*8+8) with ALL 4 gates (i/f in MFMA0, g/o in MFMA1).
// publish: agent atomic exchange of data words -> vmcnt(0) (ack: data at L3) -> agent
// atomic exchange of flag[t][W]. poll: ONE agent atomic load per lane per sweep.
// bulk h read: plain coalesced uint4 loads (flag => data at L3; start-of-kernel
// __threadfence() invalidated pre-kernel stale lines; post-publication data is
// immutable so any later cache hit is correct). Sentinel check + one-pass atomic
// fallback makes it NaN-proof even against HW prefetch of pre-publication lines.
__global__ __launch_bounds__(64, 1) void recurk(const float* __restrict__ Whh,
    const float* __restrict__ bih, const float* __restrict__ bhh,
    const unsigned short* __restrict__ G, float* __restrict__ out,
    unsigned long long* __restrict__ ring, unsigned* __restrict__ flags){
  __threadfence();   // once: drop stale L1/L2 copies of the overlaid xaug region

  const int W = ((blockIdx.x & 7) << 3) | (blockIdx.x >> 3);  // G-line-sharing waves per XCD
  const int l = threadIdx.x;
  const int b = l & 15, kq = l >> 4;
  const int hbase = W * 8;

  // A fragments resident in registers (128 VGPRs)
  bf16x8 a0[16], a1[16];
  {
    const int p = l & 15;
    const int arow0 = (p < 8) ? (hbase + p) : (512 + hbase + (p - 8));
    const int arow1 = arow0 + 1024;
    const float* w0 = Whh + (size_t)arow0 * H_;
    const float* w1 = Whh + (size_t)arow1 * H_;
    for (int kk2 = 0; kk2 < 16; ++kk2){
      const int k0 = kk2*32 + kq*8;
      float4 v0 = *(const float4*)(w0 + k0);
      float4 v1 = *(const float4*)(w0 + k0 + 4);
      bf16x8 av;
      av[0]=(short)f2bf(v0.x); av[1]=(short)f2bf(v0.y); av[2]=(short)f2bf(v0.z); av[3]=(short)f2bf(v0.w);
      av[4]=(short)f2bf(v1.x); av[5]=(short)f2bf(v1.y); av[6]=(short)f2bf(v1.z); av[7]=(short)f2bf(v1.w);
      a0[kk2] = av;
      float4 u0 = *(const float4*)(w1 + k0);
      float4 u1 = *(const float4*)(w1 + k0 + 4);
      bf16x8 bv2;
      bv2[0]=(short)f2bf(u0.x); bv2[1]=(short)f2bf(u0.y); bv2[2]=(short)f2bf(u0.z); bv2[3]=(short)f2bf(u0.w);
      bv2[4]=(short)f2bf(u1.x); bv2[5]=(short)f2bf(u1.y); bv2[6]=(short)f2bf(u1.z); bv2[7]=(short)f2bf(u1.w);
      a1[kk2] = bv2;
    }
  }
  const int col0 = ((kq < 2) ? (kq*4) : (512 + (kq-2)*4)) + hbase;
  const int col1 = col0 + 1024;
  float bias0[4], bias1[4];
  #pragma unroll
  for (int q=0;q<4;q++){
    bias0[q] = bih[col0+q] + bhh[col0+q];
    bias1[q] = bih[col1+q] + bhh[col1+q];
  }
  const bool low = (kq < 2);
  const int hcol = hbase + (low ? kq*4 : (kq-2)*4);
  const size_t ownw = (size_t)b*128 + W*2 + kq;   // low-lane's ring word (u64 idx in slot)
  float cr[4] = {0,0,0,0};

  for (int t = 0; t < S_; ++t){
    // G prefetch (cacheable) before the gate; latency hides under the wait
    const unsigned short* gp = G + ((size_t)t*16 + b) * NG;
    const short4 g0 = *(const short4*)(gp + col0);
    const short4 g1 = *(const short4*)(gp + col1);

    f32x4 acc0 = (f32x4){0,0,0,0}, acc0b = (f32x4){0,0,0,0};
    f32x4 acc1 = (f32x4){0,0,0,0}, acc1b = (f32x4){0,0,0,0};
    if (t){
      // ---- gate: lane l polls flag[t-1][l] (one agent atomic load per sweep) ----
      const unsigned* fp = flags + (size_t)(t-1)*64 + l;
      for (;;){
        unsigned f = __hip_atomic_load(fp, __ATOMIC_RELAXED, __HIP_MEMORY_SCOPE_AGENT);
        if (__all((int)f)) break;
      }
      asm volatile("" ::: "memory");   // keep data reads below the gate
      // ---- bulk h read: plain coalesced loads (flag => final data at L3) ----
      uint4 hv[16];
      const uint4* dp = (const uint4*)(ring + (size_t)(t-1)*RING_U64_PER_SLOT) + b*64 + kq;
      #pragma unroll
      for (int i = 0; i < 16; ++i) hv[i] = dp[i*4];
      unsigned ok = 1;
      #pragma unroll
      for (int i = 0; i < 16; ++i){
        ok &= (hv[i].x != SENT32) & (hv[i].y != SENT32)
            & (hv[i].z != SENT32) & (hv[i].w != SENT32);
      }
      if (!__all((int)ok)){
        // stale-cache corner (e.g. HW prefetch of a pre-publication line):
        // one-pass proven atomic re-read — flag guarantees data is at L3.
        const unsigned long long* rp64 = ring + (size_t)(t-1)*RING_U64_PER_SLOT + b*128 + kq*2;
        for (;;){
          unsigned ok2 = 1;
          #pragma unroll
          for (int i = 0; i < 16; ++i){
            unsigned long long lo = __hip_atomic_load(rp64 + i*8,     __ATOMIC_RELAXED, __HIP_MEMORY_SCOPE_AGENT);
            unsigned long long hi = __hip_atomic_load(rp64 + i*8 + 1, __ATOMIC_RELAXED, __HIP_MEMORY_SCOPE_AGENT);
            uint2 l2v = __builtin_bit_cast(uint2, lo);
            uint2 h2v = __builtin_bit_cast(uint2, hi);
            uint4 u; u.x = l2v.x; u.y = l2v.y; u.z = h2v.x; u.w = h2v.y;
            hv[i] = u;
            ok2 &= (u.x != SENT32) & (u.y != SENT32) & (u.z != SENT32) & (u.w != SENT32);
          }
          if (__all((int)ok2)) break;
        }
      }
      #pragma unroll
      for (int i = 0; i < 8; ++i){
        bf16x8 bv0 = __builtin_bit_cast(bf16x8, hv[2*i]);
        acc0  = __builtin_amdgcn_mfma_f32_16x16x32_bf16(a0[2*i],   bv0, acc0,  0, 0, 0);
        acc1  = __builtin_amdgcn_mfma_f32_16x16x32_bf16(a1[2*i],   bv0, acc1,  0, 0, 0);
        bf16x8 bv1 = __builtin_bit_cast(bf16x8, hv[2*i+1]);
        acc0b = __builtin_amdgcn_mfma_f32_16x16x32_bf16(a0[2*i+1], bv1, acc0b, 0, 0, 0);
        acc1b = __builtin_amdgcn_mfma_f32_16x16x32_bf16(a1[2*i+1], bv1, acc1b, 0, 0, 0);
      }
    }
    float ga0[4] = { bf2f((unsigned short)g0.x), bf2f((unsigned short)g0.y),
                     bf2f((unsigned short)g0.z), bf2f((unsigned short)g0.w) };
    float ga1[4] = { bf2f((unsigned short)g1.x), bf2f((unsigned short)g1.y),
                     bf2f((unsigned short)g1.z), bf2f((unsigned short)g1.w) };
    float own0[4], own1[4], oth0[4], oth1[4];
    #pragma unroll
    for (int q=0;q<4;q++){
      own0[q] = (acc0[q] + acc0b[q]) + ga0[q] + bias0[q];
      own1[q] = (acc1[q] + acc1b[q]) + ga1[q] + bias1[q];
    }
    #pragma unroll
    for (int q=0;q<4;q++){
      oth0[q] = __shfl_xor(own0[q], 32, 64);
      oth1[q] = __shfl_xor(own1[q], 32, 64);
    }
    float h4[4];
    #pragma unroll
    for (int q=0;q<4;q++){
      float iv = low ? own0[q] : oth0[q];
      float fv = low ? oth0[q] : own0[q];
      float gv = low ? own1[q] : oth1[q];
      float ov = low ? oth1[q] : own1[q];
      cr[q] = sigf(fv)*cr[q] + sigf(iv)*tanhfast(gv);
      h4[q] = sigf(ov)*tanhfast(cr[q]);
    }
    // ---- publish: data exchanges -> vmcnt(0) ack -> flag exchange ----
    if (t < S_ - 1){
      if (low){
        unsigned long long pk = (unsigned long long)f2bf(h4[0])
                              | ((unsigned long long)f2bf(h4[1]) << 16)
                              | ((unsigned long long)f2bf(h4[2]) << 32)
                              | ((unsigned long long)f2bf(h4[3]) << 48);
        __hip_atomic_exchange(ring + (size_t)t*RING_U64_PER_SLOT + ownw,
                              pk, __ATOMIC_RELAXED, __HIP_MEMORY_SCOPE_AGENT);
      }
      asm volatile("s_waitcnt vmcnt(0)" ::: "memory");   // data at L3 before flag
      if (l == 0)
        __hip_atomic_exchange(flags + (size_t)t*64 + W, 1u,
                              __ATOMIC_RELAXED, __HIP_MEMORY_SCOPE_AGENT);
    }
    // out-stores AFTER the flag: HBM ack latency off the critical path
    if (low){
      f32x4 hw4; hw4[0]=h4[0]; hw4[1]=h4[1]; hw4[2]=h4[2]; hw4[3]=h4[3];
      __builtin_nontemporal_store(hw4, (f32x4*)(out + ((size_t)b*S_ + t)*H_ + hcol));
      if (t == S_ - 1){
        float* hn = out + (size_t)B_*S_*H_;
        float* cn = hn + B_*H_;
        #pragma unroll
        for (int q=0;q<4;q++){
          hn[b*H_ + hcol + q] = h4[q];
          cn[b*H_ + hcol + q] = cr[q];
        }
      }
    }
  }
}

extern "C" void kernel_launch(void* const* d_in, const int* in_sizes, int n_in,
                              void* d_out, int out_size, void* d_ws, size_t ws_size,
                              hipStream_t stream){
  const float* x   = (const float*)d_in[0];
  const float* Wih = (const float*)d_in[1];
  const float* Whh = (const float*)d_in[2];
  const float* bih = (const float*)d_in[3];
  const float* bhh = (const float*)d_in[4];
  float* out = (float*)d_out;
  char* ws = (char*)d_ws;
  unsigned short* xaug     = (unsigned short*)(ws + OFF_XAUG);
  unsigned short* wihb     = (unsigned short*)(ws + OFF_WIHB);
  unsigned short* G        = (unsigned short*)(ws + OFF_G);
  unsigned long long* ring = (unsigned long long*)(ws + OFF_RING);   // overlays dead xaug
  unsigned* flags          = (unsigned*)(ws + OFF_FLAG);

  sigk<<<NPOS, 256, 0, stream>>>(x, xaug);
  convk<<<(NG*KP + 255)/256, 256, 0, stream>>>(Wih, wihb);
  gemmk<<<dim3(256, 16), 256, 0, stream>>>(xaug, wihb, G);
  sentk<<<1040, 256, 0, stream>>>((uint4*)(ws + OFF_RING));          // after gemmk: xaug dead
  recurk<<<64, 64, 0, stream>>>(Whh, bih, bhh, G, out, ring, flags);
}